// Round 2
// baseline (534.809 us; speedup 1.0000x reference)
//
#include <hip/hip_runtime.h>

typedef _Float16 f16;
typedef __attribute__((ext_vector_type(8))) _Float16 f16x8;
typedef __attribute__((ext_vector_type(4))) float f32x4;

#define MFMA16(a, b, c) __builtin_amdgcn_mfma_f32_16x16x32_f16((a), (b), (c), 0, 0, 0)

// ---------------------------------------------------------------------------
// Persistent kernel: 256 blocks x 256 threads (4 waves), 16 batch rows/block.
// Weights live in registers for the whole 30-step dopri5 integration.
// Transposed MFMA scheme: out^T = W^T * h^T
//   A-frag (16x32) lane l: A[i=l&15][k=(l>>4)*8+j] = W[k][n], n = nt*16+(l&15)
//   B-frag (32x16) lane l: B[k=(l>>4)*8+j][col=l&15] = h[batch=col][k]
//   D      (16x16) lane l: D[row=(l>>4)*4+r][col=l&15] -> h_next[batch=col][n]
// No d_ws usage (round-1 crash suspect: ws_size < 217KB page fault).
// ---------------------------------------------------------------------------
__global__ __launch_bounds__(256, 1) void ode_main(
        const float* __restrict__ y0, const float* __restrict__ tspan,
        const float* __restrict__ W1, const float* __restrict__ b1,
        const float* __restrict__ W2, const float* __restrict__ b2,
        const float* __restrict__ W3, const float* __restrict__ b3,
        const float* __restrict__ W4, const float* __restrict__ b4,
        float* __restrict__ out) {

    // LDS strides (f16 elems) chosen for 16B alignment + <=2-way bank aliasing.
    __shared__ f16 h0[16 * 40];    // layer-1 input, K padded to 32 (cols 13..39 zero)
    __shared__ f16 h1[16 * 264];
    __shared__ f16 h2[16 * 264];
    __shared__ f16 h3[16 * 136];
    __shared__ float ylds[208];            // y, [r*13 + c]
    __shared__ float klds[6][16 * 20];     // k1..k6, [s][r*20 + i] (i<16, >=12 are 0)
    __shared__ float bias[656];            // b1@0 b2@256 b3@512 b4@640 (pad 652..655 = 0)
    __shared__ float tsh[16];

    const int tid = threadIdx.x;
    const int l = tid & 63, w = tid >> 6;
    const int g = l >> 4, col = l & 15;    // col = batch lane within 16-row tile
    const int blk = blockIdx.x;

    // ---- gather persistent weight fragments directly from global f32 ----
    f16x8 w1f[4], w2f[4][8], w3f[2][8], w4f[4];
#pragma unroll
    for (int a = 0; a < 4; ++a) {
        const int n = (4 * w + a) * 16 + col;
#pragma unroll
        for (int j = 0; j < 8; ++j) {
            const int k = g * 8 + j;
            w1f[a][j] = (k < 13) ? (f16)W1[k * 256 + n] : (f16)0.f;
        }
    }
#pragma unroll
    for (int a = 0; a < 4; ++a) {
        const int n = (4 * w + a) * 16 + col;
#pragma unroll
        for (int kt = 0; kt < 8; ++kt)
#pragma unroll
            for (int j = 0; j < 8; ++j)
                w2f[a][kt][j] = (f16)W2[(kt * 32 + g * 8 + j) * 256 + n];
    }
#pragma unroll
    for (int a = 0; a < 2; ++a) {
        const int n = (2 * w + a) * 16 + col;
#pragma unroll
        for (int kt = 0; kt < 8; ++kt)
#pragma unroll
            for (int j = 0; j < 8; ++j)
                w3f[a][kt][j] = (f16)W3[(kt * 32 + g * 8 + j) * 128 + n];
    }
#pragma unroll
    for (int kt = 0; kt < 4; ++kt)
#pragma unroll
        for (int j = 0; j < 8; ++j)
            w4f[kt][j] = (col < 12) ? (f16)W4[(kt * 32 + g * 8 + j) * 12 + col] : (f16)0.f;

    // ---- init LDS ----
    for (int i = tid; i < 656; i += 256) {
        float v = 0.f;
        if (i < 256) v = b1[i];
        else if (i < 512) v = b2[i - 256];
        else if (i < 640) v = b3[i - 512];
        else if (i < 652) v = b4[i - 640];
        bias[i] = v;
    }
    if (tid < 16) tsh[tid] = tspan[tid];
    for (int i = tid; i < 16 * 40; i += 256) h0[i] = (f16)0.f;
    __syncthreads();
    if (tid < 208) {
        int r = tid / 13, c = tid - 13 * r;
        float v = y0[(blk * 16 + r) * 13 + c];
        ylds[tid] = v;
        h0[r * 40 + c] = (f16)v;
        out[(size_t)(blk * 16 + r) * 13 + c] = v;   // slot 0 = y0
    }
    __syncthreads();

    for (int step = 0; step < 30; ++step) {
        const float hstep = (tsh[(step >> 1) + 1] - tsh[step >> 1]) * 0.5f;
        for (int s = 0; s < 6; ++s) {
            f32x4 acc[4];
            // ---- L1: h0 -> h1 ----
            f16x8 b0 = *(const f16x8*)&h0[col * 40 + g * 8];
#pragma unroll
            for (int a = 0; a < 4; ++a) acc[a] = (f32x4){0.f, 0.f, 0.f, 0.f};
#pragma unroll
            for (int a = 0; a < 4; ++a) acc[a] = MFMA16(w1f[a], b0, acc[a]);
#pragma unroll
            for (int a = 0; a < 4; ++a) {
                int nt = 4 * w + a;
                float4 bb = *(const float4*)&bias[0 + nt * 16 + g * 4];
                float x0 = acc[a][0] + bb.x, x1 = acc[a][1] + bb.y,
                      x2 = acc[a][2] + bb.z, x3 = acc[a][3] + bb.w;
                x0 = x0 / (1.f + __expf(-x0));
                x1 = x1 / (1.f + __expf(-x1));
                x2 = x2 / (1.f + __expf(-x2));
                x3 = x3 / (1.f + __expf(-x3));
                union { f16 h[4]; uint2 u; } p;
                p.h[0] = (f16)x0; p.h[1] = (f16)x1; p.h[2] = (f16)x2; p.h[3] = (f16)x3;
                *(uint2*)&h1[col * 264 + nt * 16 + g * 4] = p.u;
            }
            __syncthreads();
            // ---- L2: h1 -> h2 ----
            f16x8 hf[8];
#pragma unroll
            for (int kt = 0; kt < 8; ++kt) hf[kt] = *(const f16x8*)&h1[col * 264 + kt * 32 + g * 8];
#pragma unroll
            for (int a = 0; a < 4; ++a) acc[a] = (f32x4){0.f, 0.f, 0.f, 0.f};
#pragma unroll
            for (int kt = 0; kt < 8; ++kt)
#pragma unroll
                for (int a = 0; a < 4; ++a) acc[a] = MFMA16(w2f[a][kt], hf[kt], acc[a]);
#pragma unroll
            for (int a = 0; a < 4; ++a) {
                int nt = 4 * w + a;
                float4 bb = *(const float4*)&bias[256 + nt * 16 + g * 4];
                float x0 = acc[a][0] + bb.x, x1 = acc[a][1] + bb.y,
                      x2 = acc[a][2] + bb.z, x3 = acc[a][3] + bb.w;
                x0 = x0 / (1.f + __expf(-x0));
                x1 = x1 / (1.f + __expf(-x1));
                x2 = x2 / (1.f + __expf(-x2));
                x3 = x3 / (1.f + __expf(-x3));
                union { f16 h[4]; uint2 u; } p;
                p.h[0] = (f16)x0; p.h[1] = (f16)x1; p.h[2] = (f16)x2; p.h[3] = (f16)x3;
                *(uint2*)&h2[col * 264 + nt * 16 + g * 4] = p.u;
            }
            __syncthreads();
            // ---- L3: h2 -> h3 ----
#pragma unroll
            for (int kt = 0; kt < 8; ++kt) hf[kt] = *(const f16x8*)&h2[col * 264 + kt * 32 + g * 8];
#pragma unroll
            for (int a = 0; a < 2; ++a) acc[a] = (f32x4){0.f, 0.f, 0.f, 0.f};
#pragma unroll
            for (int kt = 0; kt < 8; ++kt)
#pragma unroll
                for (int a = 0; a < 2; ++a) acc[a] = MFMA16(w3f[a][kt], hf[kt], acc[a]);
#pragma unroll
            for (int a = 0; a < 2; ++a) {
                int nt = 2 * w + a;
                float4 bb = *(const float4*)&bias[512 + nt * 16 + g * 4];
                float x0 = acc[a][0] + bb.x, x1 = acc[a][1] + bb.y,
                      x2 = acc[a][2] + bb.z, x3 = acc[a][3] + bb.w;
                x0 = x0 / (1.f + __expf(-x0));
                x1 = x1 / (1.f + __expf(-x1));
                x2 = x2 / (1.f + __expf(-x2));
                x3 = x3 / (1.f + __expf(-x3));
                union { f16 h[4]; uint2 u; } p;
                p.h[0] = (f16)x0; p.h[1] = (f16)x1; p.h[2] = (f16)x2; p.h[3] = (f16)x3;
                *(uint2*)&h3[col * 136 + nt * 16 + g * 4] = p.u;
            }
            __syncthreads();
            // ---- L4 (wave 3 only): h3 -> klds[s], linear, N padded 12->16 ----
            if (w == 3) {
                f16x8 h3f[4];
#pragma unroll
                for (int kt = 0; kt < 4; ++kt) h3f[kt] = *(const f16x8*)&h3[col * 136 + kt * 32 + g * 8];
                f32x4 a4 = (f32x4){0.f, 0.f, 0.f, 0.f};
#pragma unroll
                for (int kt = 0; kt < 4; ++kt) a4 = MFMA16(w4f[kt], h3f[kt], a4);
                float4 bb = *(const float4*)&bias[640 + g * 4];   // zeros for i>=12
                a4[0] += bb.x; a4[1] += bb.y; a4[2] += bb.z; a4[3] += bb.w;
                *(f32x4*)&klds[s][col * 20 + g * 4] = a4;
            }
            __syncthreads();
            // ---- RK stage combination -> next h0 (and final y update) ----
            if (tid < 208) {
                int r = tid / 13, c = tid - 13 * r;
                float v = ylds[tid];
                if (c < 12) {
#define KD(i) klds[i][r * 20 + c]
                    float y2;
                    switch (s) {
                        case 0: y2 = v + hstep * ((1.f/5.f)*KD(0)); break;
                        case 1: y2 = v + hstep * ((3.f/40.f)*KD(0) + (9.f/40.f)*KD(1)); break;
                        case 2: y2 = v + hstep * ((44.f/45.f)*KD(0) + (-56.f/15.f)*KD(1) + (32.f/9.f)*KD(2)); break;
                        case 3: y2 = v + hstep * ((19372.f/6561.f)*KD(0) + (-25360.f/2187.f)*KD(1)
                                                + (64448.f/6561.f)*KD(2) + (-212.f/729.f)*KD(3)); break;
                        case 4: y2 = v + hstep * ((9017.f/3168.f)*KD(0) + (-355.f/33.f)*KD(1)
                                                + (46732.f/5247.f)*KD(2) + (49.f/176.f)*KD(3)
                                                + (-5103.f/18656.f)*KD(4)); break;
                        default: y2 = v + hstep * ((35.f/384.f)*KD(0) + (500.f/1113.f)*KD(2)
                                                 + (125.f/192.f)*KD(3) + (-2187.f/6784.f)*KD(4)
                                                 + (11.f/84.f)*KD(5)); break;
                    }
#undef KD
                    if (s == 5) ylds[tid] = y2;
                    h0[r * 40 + c] = (f16)y2;            // c==12 stays constant from init
                    if (s == 5 && (step & 1)) {
                        int slot = (step + 1) >> 1;
                        out[((size_t)slot * 4096 + blk * 16 + r) * 13 + c] = y2;
                    }
                } else {
                    if (s == 5 && (step & 1)) {
                        int slot = (step + 1) >> 1;
                        out[((size_t)slot * 4096 + blk * 16 + r) * 13 + c] = v;
                    }
                }
            }
            __syncthreads();
        }
    }
}

extern "C" void kernel_launch(void* const* d_in, const int* in_sizes, int n_in,
                              void* d_out, int out_size, void* d_ws, size_t ws_size,
                              hipStream_t stream) {
    (void)in_sizes; (void)n_in; (void)out_size; (void)d_ws; (void)ws_size;
    const float* y0 = (const float*)d_in[0];
    const float* ts = (const float*)d_in[1];
    const float* W1 = (const float*)d_in[2];
    const float* b1 = (const float*)d_in[3];
    const float* W2 = (const float*)d_in[4];
    const float* b2 = (const float*)d_in[5];
    const float* W3 = (const float*)d_in[6];
    const float* b3 = (const float*)d_in[7];
    const float* W4 = (const float*)d_in[8];
    const float* b4 = (const float*)d_in[9];
    float* out = (float*)d_out;

    hipLaunchKernelGGL(ode_main, dim3(256), dim3(256), 0, stream,
                       y0, ts, W1, b1, W2, b2, W3, b3, W4, b4, out);
}

// Round 3
// 350.219 us; speedup vs baseline: 1.5271x; 1.5271x over previous
//
#include <hip/hip_runtime.h>

typedef _Float16 f16;
typedef __attribute__((ext_vector_type(8))) _Float16 f16x8;
typedef __attribute__((ext_vector_type(4))) float f32x4;

#define MFMA16(a, b, c) __builtin_amdgcn_mfma_f32_16x16x32_f16((a), (b), (c), 0, 0, 0)

__device__ __forceinline__ float silu_f(float x) {
    return x * __builtin_amdgcn_rcpf(1.f + __expf(-x));   // v_rcp, not full-precision div
}

__device__ __forceinline__ void pack4(f16* dst, float x0, float x1, float x2, float x3) {
    union { f16 h[4]; uint2 u; } p;
    p.h[0] = (f16)x0; p.h[1] = (f16)x1; p.h[2] = (f16)x2; p.h[3] = (f16)x3;
    *(uint2*)dst = p.u;   // 8B-aligned
}

// ---------------------------------------------------------------------------
// 256 blocks x 512 threads (8 waves), 16 batch rows/block, 2 waves/SIMD.
// Weights register-resident, split by output columns across 8 waves.
// Transposed MFMA scheme (validated round 2):
//   A-frag lane l: A[i=l&15][k=(l>>4)*8+j] ; B-frag: batch=l&15, same k
//   D lane l: rows 4*(l>>4)+j (output comp), col l&15 (batch)
// RK combine fully in registers on wave 0 (kreg[6][4] per lane).
// 4 barriers/stage.
// ---------------------------------------------------------------------------
__global__ __launch_bounds__(512, 2) void ode_main(
        const float* __restrict__ y0, const float* __restrict__ tspan,
        const float* __restrict__ W1, const float* __restrict__ b1,
        const float* __restrict__ W2, const float* __restrict__ b2,
        const float* __restrict__ W3, const float* __restrict__ b3,
        const float* __restrict__ W4, const float* __restrict__ b4,
        float* __restrict__ out) {

    __shared__ f16 h0[16 * 40];    // K padded 13->32 (cols 13..31 zero)
    __shared__ f16 h1[16 * 264];
    __shared__ f16 h2[16 * 264];
    __shared__ f16 h3[16 * 136];
    __shared__ float bias[656];    // b1@0 b2@256 b3@512 b4@640, 652..655 = 0
    __shared__ float tsh[16];

    const int tid = threadIdx.x;
    const int l = tid & 63, w = tid >> 6;   // 8 waves
    const int g = l >> 4, col = l & 15;
    const int blk = blockIdx.x;

    // ---- persistent weight fragments (per-wave N-slices) ----
    f16x8 w1f[2], w2f[2][8], w3f[8], w4f[4];
#pragma unroll
    for (int a = 0; a < 2; ++a) {
        const int n = (2 * w + a) * 16 + col;
#pragma unroll
        for (int j = 0; j < 8; ++j) {
            const int k = g * 8 + j;
            w1f[a][j] = (k < 13) ? (f16)W1[k * 256 + n] : (f16)0.f;
        }
#pragma unroll
        for (int kt = 0; kt < 8; ++kt)
#pragma unroll
            for (int j = 0; j < 8; ++j)
                w2f[a][kt][j] = (f16)W2[(kt * 32 + g * 8 + j) * 256 + n];
    }
    {
        const int n3 = w * 16 + col;
#pragma unroll
        for (int kt = 0; kt < 8; ++kt)
#pragma unroll
            for (int j = 0; j < 8; ++j)
                w3f[kt][j] = (f16)W3[(kt * 32 + g * 8 + j) * 128 + n3];
    }
#pragma unroll
    for (int kt = 0; kt < 4; ++kt)
#pragma unroll
        for (int j = 0; j < 8; ++j)
            w4f[kt][j] = (col < 12) ? (f16)W4[(kt * 32 + g * 8 + j) * 12 + col] : (f16)0.f;

    // ---- LDS init ----
    for (int i = tid; i < 656; i += 512) {
        float v = 0.f;
        if (i < 256) v = b1[i];
        else if (i < 512) v = b2[i - 256];
        else if (i < 640) v = b3[i - 512];
        else if (i < 652) v = b4[i - 640];
        bias[i] = v;
    }
    if (tid < 16) tsh[tid] = tspan[tid];
    for (int i = tid; i < 640; i += 512) h0[i] = (f16)0.f;
    __syncthreads();

    float yreg[4];
#pragma unroll
    for (int j = 0; j < 4; ++j) {
        const int c = 4 * g + j;
        yreg[j] = (c < 13) ? y0[(blk * 16 + col) * 13 + c] : 0.f;
    }
    if (w == 0) {
#pragma unroll
        for (int j = 0; j < 4; ++j) {
            const int c = 4 * g + j;
            if (c < 13) {
                h0[col * 40 + c] = (f16)yreg[j];
                out[(size_t)(blk * 16 + col) * 13 + c] = yreg[j];   // slot 0 = y0
            }
        }
    }
    __syncthreads();

    // dopri5 tableau (stage-input coefficients)
    static constexpr float AT[5][5] = {
        {0.2f, 0.f, 0.f, 0.f, 0.f},
        {3.f/40.f, 9.f/40.f, 0.f, 0.f, 0.f},
        {44.f/45.f, -56.f/15.f, 32.f/9.f, 0.f, 0.f},
        {19372.f/6561.f, -25360.f/2187.f, 64448.f/6561.f, -212.f/729.f, 0.f},
        {9017.f/3168.f, -355.f/33.f, 46732.f/5247.f, 49.f/176.f, -5103.f/18656.f}
    };

    float kreg[6][4];

    for (int step = 0; step < 30; ++step) {
        const float hstep = (tsh[(step >> 1) + 1] - tsh[step >> 1]) * 0.5f;
#pragma unroll
        for (int s = 0; s < 6; ++s) {
            // ---- L1: h0 -> h1 (2 nt-tiles per wave) ----
            f16x8 b0 = *(const f16x8*)&h0[col * 40 + g * 8];
            f32x4 acc[2];
#pragma unroll
            for (int a = 0; a < 2; ++a) acc[a] = (f32x4){0.f, 0.f, 0.f, 0.f};
#pragma unroll
            for (int a = 0; a < 2; ++a) acc[a] = MFMA16(w1f[a], b0, acc[a]);
#pragma unroll
            for (int a = 0; a < 2; ++a) {
                const int nt = 2 * w + a;
                float4 bb = *(const float4*)&bias[nt * 16 + g * 4];
                pack4(&h1[col * 264 + nt * 16 + g * 4],
                      silu_f(acc[a][0] + bb.x), silu_f(acc[a][1] + bb.y),
                      silu_f(acc[a][2] + bb.z), silu_f(acc[a][3] + bb.w));
            }
            __syncthreads();
            // ---- L2: h1 -> h2 ----
            f16x8 hf[8];
#pragma unroll
            for (int kt = 0; kt < 8; ++kt) hf[kt] = *(const f16x8*)&h1[col * 264 + kt * 32 + g * 8];
#pragma unroll
            for (int a = 0; a < 2; ++a) acc[a] = (f32x4){0.f, 0.f, 0.f, 0.f};
#pragma unroll
            for (int kt = 0; kt < 8; ++kt)
#pragma unroll
                for (int a = 0; a < 2; ++a) acc[a] = MFMA16(w2f[a][kt], hf[kt], acc[a]);
#pragma unroll
            for (int a = 0; a < 2; ++a) {
                const int nt = 2 * w + a;
                float4 bb = *(const float4*)&bias[256 + nt * 16 + g * 4];
                pack4(&h2[col * 264 + nt * 16 + g * 4],
                      silu_f(acc[a][0] + bb.x), silu_f(acc[a][1] + bb.y),
                      silu_f(acc[a][2] + bb.z), silu_f(acc[a][3] + bb.w));
            }
            __syncthreads();
            // ---- L3: h2 -> h3 (1 nt-tile per wave) ----
#pragma unroll
            for (int kt = 0; kt < 8; ++kt) hf[kt] = *(const f16x8*)&h2[col * 264 + kt * 32 + g * 8];
            f32x4 a3 = (f32x4){0.f, 0.f, 0.f, 0.f};
#pragma unroll
            for (int kt = 0; kt < 8; ++kt) a3 = MFMA16(w3f[kt], hf[kt], a3);
            {
                float4 bb = *(const float4*)&bias[512 + w * 16 + g * 4];
                pack4(&h3[col * 136 + w * 16 + g * 4],
                      silu_f(a3[0] + bb.x), silu_f(a3[1] + bb.y),
                      silu_f(a3[2] + bb.z), silu_f(a3[3] + bb.w));
            }
            __syncthreads();
            // ---- L4 + in-register RK (wave 0 only) ----
            if (w == 0) {
                f16x8 h3f[4];
#pragma unroll
                for (int kt = 0; kt < 4; ++kt) h3f[kt] = *(const f16x8*)&h3[col * 136 + kt * 32 + g * 8];
                f32x4 a4 = (f32x4){0.f, 0.f, 0.f, 0.f};
#pragma unroll
                for (int kt = 0; kt < 4; ++kt) a4 = MFMA16(w4f[kt], h3f[kt], a4);
                float4 bb = *(const float4*)&bias[640 + g * 4];   // zeros for c>=12
                kreg[s][0] = a4[0] + bb.x; kreg[s][1] = a4[1] + bb.y;
                kreg[s][2] = a4[2] + bb.z; kreg[s][3] = a4[3] + bb.w;
                float x[4];
                if (s < 5) {
#pragma unroll
                    for (int j = 0; j < 4; ++j) {
                        float a2 = 0.f;
#pragma unroll
                        for (int i = 0; i <= s; ++i) a2 += AT[s][i] * kreg[i][j];
                        x[j] = yreg[j] + hstep * a2;
                    }
                } else {
#pragma unroll
                    for (int j = 0; j < 4; ++j) {
                        float a2 = (35.f/384.f) * kreg[0][j] + (500.f/1113.f) * kreg[2][j]
                                 + (125.f/192.f) * kreg[3][j] + (-2187.f/6784.f) * kreg[4][j]
                                 + (11.f/84.f) * kreg[5][j];
                        yreg[j] += hstep * a2;
                        x[j] = yreg[j];
                    }
                }
                pack4(&h0[col * 40 + g * 4], x[0], x[1], x[2], x[3]);   // cols 12..15: (y12,0,0,0)
                if (s == 5 && (step & 1)) {
                    const int slot = (step + 1) >> 1;
#pragma unroll
                    for (int j = 0; j < 4; ++j) {
                        const int c = 4 * g + j;
                        if (c < 13)
                            out[((size_t)slot * 4096 + blk * 16 + col) * 13 + c] = yreg[j];
                    }
                }
            }
            __syncthreads();
        }
    }
}

extern "C" void kernel_launch(void* const* d_in, const int* in_sizes, int n_in,
                              void* d_out, int out_size, void* d_ws, size_t ws_size,
                              hipStream_t stream) {
    (void)in_sizes; (void)n_in; (void)out_size; (void)d_ws; (void)ws_size;
    const float* y0 = (const float*)d_in[0];
    const float* ts = (const float*)d_in[1];
    const float* W1 = (const float*)d_in[2];
    const float* b1 = (const float*)d_in[3];
    const float* W2 = (const float*)d_in[4];
    const float* b2 = (const float*)d_in[5];
    const float* W3 = (const float*)d_in[6];
    const float* b3 = (const float*)d_in[7];
    const float* W4 = (const float*)d_in[8];
    const float* b4 = (const float*)d_in[9];
    float* out = (float*)d_out;

    hipLaunchKernelGGL(ode_main, dim3(256), dim3(512), 0, stream,
                       y0, ts, W1, b1, W2, b2, W3, b3, W4, b4, out);
}